// Round 2
// baseline (358.772 us; speedup 1.0000x reference)
//
#include <hip/hip_runtime.h>

// GraphSAGE 3-layer forward, MI355X. Round 11 (= round 10 + gather MLP fix):
//   R10 counters: fused_layer VGPR_Count=32 -> compiler serialized the 8
//   gather row-loads (needs >32 regs to keep them in flight). MfmaUtil 2%,
//   VALUBusy 22%, HBM 24%: pure latency-bound. Fix:
//   - inline-asm batched gather: 16x global_load_dwordx2 issued back-to-back,
//     ONE manual s_waitcnt vmcnt(0) + sched_barrier(0), then accumulate.
//     Compiler cannot serialize asm loads -> MLP 16 per half-wave.
//   - elist segments 4-aligned (padded scan in bucket_place, SLOT 5120->5632)
//     so edge indices load as int4 (4 uniform loads/batch instead of 16).
//   - same treatment for gather64_add; launch_bounds(256,4) everywhere.

constexpr int N = 50000;
constexpr int E = 800000;
constexpr int NBUCK = (N + 255) / 256;    // 196 dst-buckets (256 nodes each)
constexpr int CE = 2048;                  // edges per scatter chunk
constexpr int NEB = (E + CE - 1) / CE;    // 391
constexpr int SLOT = 5632;                // padded slab: 4096 exp + 5sig(320) + align pad(<=768)
static_assert(N <= 65536, "u16 packing");

typedef _Float16 f16x8 __attribute__((ext_vector_type(8)));
typedef _Float16 f16x4 __attribute__((ext_vector_type(4)));
typedef _Float16 f16x2 __attribute__((ext_vector_type(2)));
typedef float f32x4 __attribute__((ext_vector_type(4)));

// ---- asm gather primitives: loads the compiler cannot serialize ----------
__device__ __forceinline__ f16x4 gload_b64(const _Float16* p) {
  f16x4 r;
  asm volatile("global_load_dwordx2 %0, %1, off" : "=v"(r) : "v"(p));
  return r;
}
__device__ __forceinline__ f16x2 gload_b32(const _Float16* p) {
  f16x2 r;
  asm volatile("global_load_dword %0, %1, off" : "=v"(r) : "v"(p));
  return r;
}
__device__ __forceinline__ void vmwait0() {
  asm volatile("s_waitcnt vmcnt(0)" ::: "memory");
  __builtin_amdgcn_sched_barrier(0);   // rule #18: keep uses below the wait
}

// ---------------- CSR build (padded buckets; no global hist/scan) ----------

// Phase A: LDS counting sort of a CE-edge chunk by dst>>8; append grouped
// runs of packed (dst<<16|src) into each bucket's padded slab of T.
__global__ __launch_bounds__(256) void bucket_scatter_kernel(
    const int* __restrict__ src, const int* __restrict__ dst,
    int* __restrict__ bcur, unsigned* __restrict__ T) {
  __shared__ unsigned sorted[CE];
  __shared__ int hist[256], scan[256], excl[256], lcur[256], gbase[256];
  const int t = threadIdx.x;
  const int e0 = blockIdx.x * CE;
  const int nval = min(CE, E - e0);
  hist[t] = 0;
  __syncthreads();
  for (int i = t; i < nval; i += 256) atomicAdd(&hist[dst[e0 + i] >> 8], 1);
  __syncthreads();
  const int h = hist[t];
  scan[t] = h;
  __syncthreads();
  for (int off = 1; off < 256; off <<= 1) {
    int u = (t >= off) ? scan[t - off] : 0;
    __syncthreads();
    scan[t] += u;
    __syncthreads();
  }
  excl[t] = scan[t] - h;
  lcur[t] = scan[t] - h;
  gbase[t] = (t < NBUCK && h > 0) ? atomicAdd(&bcur[t], h) : 0;
  __syncthreads();
  for (int i = t; i < nval; i += 256) {
    int e = e0 + i;
    int d = dst[e];
    int p = atomicAdd(&lcur[d >> 8], 1);
    sorted[p] = ((unsigned)d << 16) | (unsigned)src[e];
  }
  __syncthreads();
  for (int i = t; i < nval; i += 256) {
    unsigned pk = sorted[i];
    int b = pk >> 24;                     // == dst>>8
    T[gbase[b] + (i - excl[b])] = pk;
  }
}

// Phase B: one block per bucket. Derive per-node offsets/degrees (LDS hist +
// scan over 4-ALIGNED degrees so every elist segment starts at e%4==0),
// write offs+deg, place edges into exact slots of the padded elist.
__global__ __launch_bounds__(256) void bucket_place_kernel(
    const unsigned* __restrict__ T, const int* __restrict__ bcur,
    int* __restrict__ offs, int* __restrict__ deg, int* __restrict__ elist) {
  __shared__ int dcnt[256], s[256], ncur[256];
  const int t = threadIdx.x;
  const int b = blockIdx.x;
  const int lo = b * SLOT;
  const int hi = bcur[b];                 // lo + edges-in-bucket
  dcnt[t] = 0;
  __syncthreads();
  for (int i = lo + t; i < hi; i += 256) atomicAdd(&dcnt[(T[i] >> 16) & 255], 1);
  __syncthreads();
  const int v = dcnt[t];
  const int pv = (v + 3) & ~3;            // 4-aligned segment length
  s[t] = pv;
  __syncthreads();
  for (int off = 1; off < 256; off <<= 1) {
    int u = (t >= off) ? s[t - off] : 0;
    __syncthreads();
    s[t] += u;
    __syncthreads();
  }
  const int base = lo + s[t] - pv;        // within-bucket exclusive + slab base
  const int node = b * 256 + t;
  if (node < N) { offs[node] = base; deg[node] = v; }
  ncur[t] = base;
  __syncthreads();
  for (int i = lo + t; i < hi; i += 256) {
    unsigned pk = T[i];
    int pos = atomicAdd(&ncur[(pk >> 16) & 255], 1);
    elist[pos] = (int)(pk & 0xffffu);
  }
}

// ---------------- fused setup: convert + wfrag tables + bcur init ----------
// Wf[((ct*KB+kb)*64+lane)*8+j] = Wcat[ct*16+(lane&15)][kb*32+(lane>>4)*8+j]
__device__ inline void wfrag_build(int idx, int KB, const float* wl,
                                   const float* wr, _Float16* wf) {
  int j = idx & 7;
  int lane = (idx >> 3) & 63;
  int kb = (idx >> 9) % KB;
  int ct = (idx >> 9) / KB;
  int c = ct * 16 + (lane & 15);
  int k = kb * 32 + (lane >> 4) * 8 + j;
  float v = (k < 128) ? wl[c * 128 + k] : wr[c * 128 + (k - 128)];
  wf[idx] = (_Float16)v;
}

constexpr int CONVB = (N * 128 / 8 + 255) / 256;   // 3125 convert blocks

__global__ __launch_bounds__(256) void setup_kernel(
    const float* __restrict__ x,
    const float* __restrict__ wl0, const float* __restrict__ wr0,
    const float* __restrict__ wl1, const float* __restrict__ wr1,
    const float* __restrict__ wl2, const float* __restrict__ wr2,
    _Float16* __restrict__ HA, _Float16* __restrict__ wf0,
    _Float16* __restrict__ wf1, _Float16* __restrict__ wfZ,
    int* __restrict__ bcur) {
  const int b = blockIdx.x;
  const int t = threadIdx.x;
  if (b < CONVB) {
    int i = b * 256 + t;                  // one thread per 8 elems
    if (i < N * 128 / 8) {
      float4 a = ((const float4*)x)[i * 2];
      float4 c = ((const float4*)x)[i * 2 + 1];
      f16x8 v;
      v[0] = (_Float16)a.x; v[1] = (_Float16)a.y; v[2] = (_Float16)a.z; v[3] = (_Float16)a.w;
      v[4] = (_Float16)c.x; v[5] = (_Float16)c.y; v[6] = (_Float16)c.z; v[7] = (_Float16)c.w;
      ((f16x8*)HA)[i] = v;
    }
  } else if (b < CONVB + 128) {           // wf0: [wl0|wr0], K=256 (32768 = 128 blk)
    wfrag_build((b - CONVB) * 256 + t, 8, wl0, wr0, wf0);
  } else if (b < CONVB + 256) {           // wf1: [wl1|wr1]
    wfrag_build((b - CONVB - 128) * 256 + t, 8, wl1, wr1, wf1);
  } else if (b < CONVB + 320) {           // wfZ: 8ct*4kb*512 = 16384 = 64 blocks
    int idx = (b - CONVB - 256) * 256 + t;
    int j = idx & 7;
    int lane = (idx >> 3) & 63;
    int kb = (idx >> 9) & 3;
    int ct = idx >> 11;                   // 0..7
    int c = ct * 16 + (lane & 15);
    int k = kb * 32 + (lane >> 4) * 8 + j;
    float v = (c < 64) ? wl2[c * 128 + k] : wr2[(c - 64) * 128 + k];
    wfZ[idx] = (_Float16)v;
  } else {                                // bcur init (1 block)
    if (t < NBUCK) bcur[t] = t * SLOT;
  }
}

// ---------------- fused layer: gather-mean -> LDS frags -> MFMA GEMM -------
// One block = 32 output rows. Phase 1a: stage own H rows into frag-ordered
// LDS (kb 4-7). Phase 1b: half-wave-per-node gather-mean with asm-batched
// loads (16 rows in flight) into frag-ordered LDS (kb 0-3). Phase 2: 4 waves
// x 32 cols GEMM, A from LDS, B frags from global (L2-resident 64 KB table).
__global__ __launch_bounds__(256, 4) void fused_layer_kernel(
    const _Float16* __restrict__ H, const int* __restrict__ offs,
    const int* __restrict__ deg, const int* __restrict__ elist,
    const _Float16* __restrict__ Wf, const float* __restrict__ bias,
    const float* __restrict__ U, _Float16* __restrict__ outp) {
  __shared__ __align__(16) _Float16 Af[2][8][64][8];   // [h][kb][lane][j] 16 KB
  const int t = threadIdx.x;
  const int rowbase = blockIdx.x * 32;

  // phase 1a: own H rows -> Af[.][4..7][.][.]  (512 octets, 2 per thread)
#pragma unroll
  for (int m2 = 0; m2 < 2; ++m2) {
    int m = t * 2 + m2;
    int r = m >> 4, o = m & 15;           // r: 0..31 row, o: 0..15 octet
    int row = min(rowbase + r, N - 1);    // clamp feeds only discarded rows
    f16x8 v = *(const f16x8*)(H + (size_t)row * 128 + o * 8);
    *(f16x8*)&Af[r >> 4][4 + (o >> 2)][(o & 3) * 16 + (r & 15)][0] = v;
  }

  // phase 1b: gather-mean -> Af[.][0..3][.][.]; half-wave (32 lanes) per node
  {
    const int hw = t >> 5;                // 0..7
    const int ll = t & 31;                // cols 4*ll .. 4*ll+3
    const int kb = ll >> 3, q = (ll >> 1) & 3, j = (ll & 1) * 4;
#pragma unroll 1
    for (int i = 0; i < 4; ++i) {
      int r = hw * 4 + i;
      int node = rowbase + r;
      float a0 = 0.f, a1 = 0.f, a2 = 0.f, a3 = 0.f;
      int d = 0;
      if (node < N) {
        const int e0 = offs[node];        // e0 % 4 == 0 (padded scan)
        d = deg[node];
        const int e1 = e0 + d;
        int e = e0;
        for (; e + 16 <= e1; e += 16) {
          int4 q0 = *(const int4*)(elist + e);
          int4 q1 = *(const int4*)(elist + e + 4);
          int4 q2 = *(const int4*)(elist + e + 8);
          int4 q3 = *(const int4*)(elist + e + 12);
          int s[16] = {q0.x, q0.y, q0.z, q0.w, q1.x, q1.y, q1.z, q1.w,
                       q2.x, q2.y, q2.z, q2.w, q3.x, q3.y, q3.z, q3.w};
          f16x4 v[16];
#pragma unroll
          for (int u = 0; u < 16; ++u)
            v[u] = gload_b64(H + (size_t)s[u] * 128 + ll * 4);
          vmwait0();
#pragma unroll
          for (int u = 0; u < 16; ++u) {
            a0 += (float)v[u][0]; a1 += (float)v[u][1];
            a2 += (float)v[u][2]; a3 += (float)v[u][3];
          }
        }
        for (; e + 4 <= e1; e += 4) {
          int4 qq4 = *(const int4*)(elist + e);
          int s[4] = {qq4.x, qq4.y, qq4.z, qq4.w};
          f16x4 v[4];
#pragma unroll
          for (int u = 0; u < 4; ++u)
            v[u] = gload_b64(H + (size_t)s[u] * 128 + ll * 4);
          vmwait0();
#pragma unroll
          for (int u = 0; u < 4; ++u) {
            a0 += (float)v[u][0]; a1 += (float)v[u][1];
            a2 += (float)v[u][2]; a3 += (float)v[u][3];
          }
        }
        for (; e < e1; ++e) {
          f16x4 v = *(const f16x4*)(H + (size_t)elist[e] * 128 + ll * 4);
          a0 += (float)v[0]; a1 += (float)v[1];
          a2 += (float)v[2]; a3 += (float)v[3];
        }
      }
      float inv = 1.0f / (float)max(d, 1);
      f16x4 o;
      o[0] = (_Float16)(a0 * inv); o[1] = (_Float16)(a1 * inv);
      o[2] = (_Float16)(a2 * inv); o[3] = (_Float16)(a3 * inv);
      *(f16x4*)&Af[r >> 4][kb][q * 16 + (r & 15)][j] = o;
    }
  }
  __syncthreads();

  // phase 2: GEMM. Wave w covers cols w*32..w*32+31.
  const int lane = t & 63;
  const int w = t >> 6;
  const int n16 = lane & 15;
  const int qq = lane >> 4;
  const int colbase = w * 32;

  f32x4 acc[2][2];
#pragma unroll
  for (int h = 0; h < 2; ++h)
#pragma unroll
    for (int ct = 0; ct < 2; ++ct) acc[h][ct] = (f32x4){0.f, 0.f, 0.f, 0.f};

#pragma unroll
  for (int kb = 0; kb < 8; ++kb) {
    f16x8 a0 = *(const f16x8*)&Af[0][kb][lane][0];
    f16x8 a1 = *(const f16x8*)&Af[1][kb][lane][0];
#pragma unroll
    for (int ct = 0; ct < 2; ++ct) {
      const int ctg = w * 2 + ct;
      f16x8 b = *(const f16x8*)(Wf + ((size_t)(ctg * 8 + kb) * 64 + lane) * 8);
      acc[0][ct] = __builtin_amdgcn_mfma_f32_16x16x32_f16(a0, b, acc[0][ct], 0, 0, 0);
      acc[1][ct] = __builtin_amdgcn_mfma_f32_16x16x32_f16(a1, b, acc[1][ct], 0, 0, 0);
    }
  }

  // C/D layout: col = lane&15, row = (lane>>4)*4 + reg
#pragma unroll
  for (int h = 0; h < 2; ++h) {
#pragma unroll
    for (int ct = 0; ct < 2; ++ct) {
      const int col = colbase + ct * 16 + n16;
      const float bv = bias[col];
#pragma unroll
      for (int r = 0; r < 4; ++r) {
        int row = rowbase + h * 16 + qq * 4 + r;
        if (row < N) {
          float v = fmaxf(acc[h][ct][r] + bv, 0.f);
          float u = U[(size_t)row * 128 + col];
          v *= (u >= 0.3f) ? (1.0f / 0.7f) : 0.0f;
          outp[(size_t)row * 128 + col] = (_Float16)v;
        }
      }
    }
  }
}

// ---------------- gather64 + final add: out = F + mean(Y2[nbrs]) ----------
// Half-wave (32 lanes x f16x2) per node; asm-batched (16 rows in flight);
// writes f32 d_out directly.
__global__ __launch_bounds__(256, 4) void gather64_add_kernel(
    const _Float16* __restrict__ Y2, const float* __restrict__ F,
    const int* __restrict__ offs, const int* __restrict__ deg,
    const int* __restrict__ elist, float* __restrict__ out) {
  int node = blockIdx.x * 8 + (threadIdx.x >> 5);
  if (node >= N) return;
  int l = threadIdx.x & 31;
  const int e0 = offs[node];              // e0 % 4 == 0
  const int d = deg[node];
  const int e1 = e0 + d;
  float a0 = 0.f, a1 = 0.f;
  int e = e0;
  for (; e + 16 <= e1; e += 16) {
    int4 q0 = *(const int4*)(elist + e);
    int4 q1 = *(const int4*)(elist + e + 4);
    int4 q2 = *(const int4*)(elist + e + 8);
    int4 q3 = *(const int4*)(elist + e + 12);
    int s[16] = {q0.x, q0.y, q0.z, q0.w, q1.x, q1.y, q1.z, q1.w,
                 q2.x, q2.y, q2.z, q2.w, q3.x, q3.y, q3.z, q3.w};
    f16x2 v[16];
#pragma unroll
    for (int u = 0; u < 16; ++u)
      v[u] = gload_b32(Y2 + (size_t)s[u] * 64 + l * 2);
    vmwait0();
#pragma unroll
    for (int u = 0; u < 16; ++u) { a0 += (float)v[u][0]; a1 += (float)v[u][1]; }
  }
  for (; e + 4 <= e1; e += 4) {
    int4 q = *(const int4*)(elist + e);
    int s[4] = {q.x, q.y, q.z, q.w};
    f16x2 v[4];
#pragma unroll
    for (int u = 0; u < 4; ++u)
      v[u] = gload_b32(Y2 + (size_t)s[u] * 64 + l * 2);
    vmwait0();
#pragma unroll
    for (int u = 0; u < 4; ++u) { a0 += (float)v[u][0]; a1 += (float)v[u][1]; }
  }
  for (; e < e1; ++e) {
    f16x2 v = *(const f16x2*)(Y2 + (size_t)elist[e] * 64 + l * 2);
    a0 += (float)v[0]; a1 += (float)v[1];
  }
  float inv = 1.0f / (float)max(d, 1);
  float2 f = ((const float2*)(F + (size_t)node * 64))[l];
  float2 o;
  o.x = f.x + a0 * inv;
  o.y = f.y + a1 * inv;
  ((float2*)(out + (size_t)node * 64))[l] = o;
}

// ---------------- layer-2 Z GEMM: cols 0-63 -> Y2=H@wl2^T (f16);
//                  cols 64-127 -> F=H@wr2^T+bl2 (f32). K=128.
__global__ __launch_bounds__(256, 4) void mfma_gemmZ_kernel(
    const _Float16* __restrict__ Hh, const _Float16* __restrict__ Wf,
    const float* __restrict__ bl2, _Float16* __restrict__ Y2,
    float* __restrict__ F) {
  const int lane = threadIdx.x & 63;
  const int w = threadIdx.x >> 6;
  const int n16 = lane & 15;
  const int q = lane >> 4;
  const int rowbase = blockIdx.x * 32;
  const int colbase = w * 32;

  f32x4 acc[2][2];
#pragma unroll
  for (int h = 0; h < 2; ++h)
#pragma unroll
    for (int ct = 0; ct < 2; ++ct) acc[h][ct] = (f32x4){0.f, 0.f, 0.f, 0.f};

  int ar0 = min(rowbase + n16, N - 1);
  int ar1 = min(rowbase + 16 + n16, N - 1);
  const _Float16* pH0 = Hh + (size_t)ar0 * 128 + q * 8;
  const _Float16* pH1 = Hh + (size_t)ar1 * 128 + q * 8;

#pragma unroll
  for (int kb = 0; kb < 4; ++kb) {
    const int ko = kb * 32;
    f16x8 a0 = *(const f16x8*)(pH0 + ko);
    f16x8 a1 = *(const f16x8*)(pH1 + ko);
#pragma unroll
    for (int ct = 0; ct < 2; ++ct) {
      const int ctg = w * 2 + ct;
      f16x8 b = *(const f16x8*)(Wf + ((size_t)(ctg * 4 + kb) * 64 + lane) * 8);
      acc[0][ct] = __builtin_amdgcn_mfma_f32_16x16x32_f16(a0, b, acc[0][ct], 0, 0, 0);
      acc[1][ct] = __builtin_amdgcn_mfma_f32_16x16x32_f16(a1, b, acc[1][ct], 0, 0, 0);
    }
  }

#pragma unroll
  for (int h = 0; h < 2; ++h) {
#pragma unroll
    for (int ct = 0; ct < 2; ++ct) {
      const int col = colbase + ct * 16 + n16;
#pragma unroll
      for (int r = 0; r < 4; ++r) {
        int row = rowbase + h * 16 + q * 4 + r;
        if (row < N) {
          float v = acc[h][ct][r];
          if (col < 64) Y2[(size_t)row * 64 + col] = (_Float16)v;
          else F[(size_t)row * 64 + (col - 64)] = v + bl2[col - 64];
        }
      }
    }
  }
}

extern "C" void kernel_launch(void* const* d_in, const int* in_sizes, int n_in,
                              void* d_out, int out_size, void* d_ws, size_t ws_size,
                              hipStream_t stream) {
  const float* x   = (const float*)d_in[0];
  const float* u1  = (const float*)d_in[1];
  const float* u2  = (const float*)d_in[2];
  const float* wl0 = (const float*)d_in[3];
  const float* bl0 = (const float*)d_in[4];
  const float* wr0 = (const float*)d_in[5];
  const float* wl1 = (const float*)d_in[6];
  const float* bl1 = (const float*)d_in[7];
  const float* wr1 = (const float*)d_in[8];
  const float* wl2 = (const float*)d_in[9];
  const float* bl2 = (const float*)d_in[10];
  const float* wr2 = (const float*)d_in[11];
  const int* edge  = (const int*)d_in[12];
  const int* src = edge;
  const int* dst = edge + E;

  // workspace layout
  _Float16* HA  = (_Float16*)d_ws;                 // N x 128 f16
  _Float16* HB  = HA + (size_t)N * 128;            // N x 128 f16
  _Float16* M16 = HB + (size_t)N * 128;            // N x 128 f16 (Y2 in layer 2)
  float* F      = (float*)(M16 + (size_t)N * 128); // N x 64 f32
  int* offs     = (int*)(F + (size_t)N * 64);      // N
  int* deg      = offs + N;                        // N
  int* elist    = deg + N;                         // NBUCK*SLOT (padded)
  unsigned* T   = (unsigned*)(elist + NBUCK * SLOT);
  int* bcur     = (int*)(T + NBUCK * SLOT);        // NBUCK
  uintptr_t p = (uintptr_t)(bcur + NBUCK);
  p = (p + 15) & ~(uintptr_t)15;
  _Float16* wf0 = (_Float16*)p;                    // 8*8*512
  _Float16* wf1 = wf0 + 8 * 8 * 512;
  _Float16* wfZ = wf1 + 8 * 8 * 512;               // 8*4*512

  // 1) setup: convert + 3 wfrag tables + bcur init
  setup_kernel<<<CONVB + 321, 256, 0, stream>>>(
      x, wl0, wr0, wl1, wr1, wl2, wr2, HA, wf0, wf1, wfZ, bcur);
  // 2-3) CSR build
  bucket_scatter_kernel<<<NEB, 256, 0, stream>>>(src, dst, bcur, T);
  bucket_place_kernel<<<NBUCK, 256, 0, stream>>>(T, bcur, offs, deg, elist);

  const int GM   = (N + 31) / 32;      // 32 rows/block
  const int GG64 = (N + 7) / 8;        // half-wave per node

  // ---- Layer 0 (fused gather+GEMM) ----
  fused_layer_kernel<<<GM, 256, 0, stream>>>(HA, offs, deg, elist, wf0, bl0, u1, HB);
  // ---- Layer 1 (fused gather+GEMM) ----
  fused_layer_kernel<<<GM, 256, 0, stream>>>(HB, offs, deg, elist, wf1, bl1, u2, HA);
  // ---- Layer 2 ----
  mfma_gemmZ_kernel<<<GM, 256, 0, stream>>>(HA, wfZ, bl2, M16, F);
  gather64_add_kernel<<<GG64, 256, 0, stream>>>(M16, F, offs, deg, elist,
                                                (float*)d_out);
}

// Round 3
// 314.161 us; speedup vs baseline: 1.1420x; 1.1420x over previous
//
#include <hip/hip_runtime.h>

// GraphSAGE 3-layer forward, MI355X. Round 12:
//   R11 post-mortem: asm-batched gather REGRESSED (57.9->85.7us/layer).
//   VGPR 32->40 only => compiler already had ~8 loads in flight in R10; the
//   asm+sched walls broke its scheduling. Gather is THROUGHPUT-bound:
//   205MB row traffic / 57.9us = 3.5 TB/s effective L2/L3 delivery.
//   => Revert to plain-C gather (R10) and cut BYTES instead:
//   - dropout U (25.6MB f32 per layer, read inside the slow kernel, polluting
//     L2/L3) replaced by bit-packed masks built in setup via __ballot
//     (800KB/layer, L2-resident). Setup absorbs the 51.2MB u1/u2 stream at
//     ~6 TB/s instead of the fused layer's ~2-3.5 TB/s effective rate.
//   - keep 4-aligned elist segments + int4 index loads (plain C, no asm).

constexpr int N = 50000;
constexpr int E = 800000;
constexpr int NBUCK = (N + 255) / 256;    // 196 dst-buckets (256 nodes each)
constexpr int CE = 2048;                  // edges per scatter chunk
constexpr int NEB = (E + CE - 1) / CE;    // 391
constexpr int SLOT = 5632;                // padded slab (exp 4096 + sigma + 4-align pad)
static_assert(N <= 65536, "u16 packing");

typedef _Float16 f16x8 __attribute__((ext_vector_type(8)));
typedef _Float16 f16x4 __attribute__((ext_vector_type(4)));
typedef _Float16 f16x2 __attribute__((ext_vector_type(2)));
typedef float f32x4 __attribute__((ext_vector_type(4)));

// ---------------- CSR build (padded buckets; no global hist/scan) ----------

// Phase A: LDS counting sort of a CE-edge chunk by dst>>8; append grouped
// runs of packed (dst<<16|src) into each bucket's padded slab of T.
__global__ __launch_bounds__(256) void bucket_scatter_kernel(
    const int* __restrict__ src, const int* __restrict__ dst,
    int* __restrict__ bcur, unsigned* __restrict__ T) {
  __shared__ unsigned sorted[CE];
  __shared__ int hist[256], scan[256], excl[256], lcur[256], gbase[256];
  const int t = threadIdx.x;
  const int e0 = blockIdx.x * CE;
  const int nval = min(CE, E - e0);
  hist[t] = 0;
  __syncthreads();
  for (int i = t; i < nval; i += 256) atomicAdd(&hist[dst[e0 + i] >> 8], 1);
  __syncthreads();
  const int h = hist[t];
  scan[t] = h;
  __syncthreads();
  for (int off = 1; off < 256; off <<= 1) {
    int u = (t >= off) ? scan[t - off] : 0;
    __syncthreads();
    scan[t] += u;
    __syncthreads();
  }
  excl[t] = scan[t] - h;
  lcur[t] = scan[t] - h;
  gbase[t] = (t < NBUCK && h > 0) ? atomicAdd(&bcur[t], h) : 0;
  __syncthreads();
  for (int i = t; i < nval; i += 256) {
    int e = e0 + i;
    int d = dst[e];
    int p = atomicAdd(&lcur[d >> 8], 1);
    sorted[p] = ((unsigned)d << 16) | (unsigned)src[e];
  }
  __syncthreads();
  for (int i = t; i < nval; i += 256) {
    unsigned pk = sorted[i];
    int b = pk >> 24;                     // == dst>>8
    T[gbase[b] + (i - excl[b])] = pk;
  }
}

// Phase B: one block per bucket. Derive per-node offsets/degrees (LDS hist +
// scan over 4-ALIGNED degrees so every elist segment starts at e%4==0),
// write offs+deg, place edges into exact slots of the padded elist.
__global__ __launch_bounds__(256) void bucket_place_kernel(
    const unsigned* __restrict__ T, const int* __restrict__ bcur,
    int* __restrict__ offs, int* __restrict__ deg, int* __restrict__ elist) {
  __shared__ int dcnt[256], s[256], ncur[256];
  const int t = threadIdx.x;
  const int b = blockIdx.x;
  const int lo = b * SLOT;
  const int hi = bcur[b];                 // lo + edges-in-bucket
  dcnt[t] = 0;
  __syncthreads();
  for (int i = lo + t; i < hi; i += 256) atomicAdd(&dcnt[(T[i] >> 16) & 255], 1);
  __syncthreads();
  const int v = dcnt[t];
  const int pv = (v + 3) & ~3;            // 4-aligned segment length
  s[t] = pv;
  __syncthreads();
  for (int off = 1; off < 256; off <<= 1) {
    int u = (t >= off) ? s[t - off] : 0;
    __syncthreads();
    s[t] += u;
    __syncthreads();
  }
  const int base = lo + s[t] - pv;        // within-bucket exclusive + slab base
  const int node = b * 256 + t;
  if (node < N) { offs[node] = base; deg[node] = v; }
  ncur[t] = base;
  __syncthreads();
  for (int i = lo + t; i < hi; i += 256) {
    unsigned pk = T[i];
    int pos = atomicAdd(&ncur[(pk >> 16) & 255], 1);
    elist[pos] = (int)(pk & 0xffffu);
  }
}

// ---------------- fused setup: convert + wfrag tables + masks + bcur -------
// Wf[((ct*KB+kb)*64+lane)*8+j] = Wcat[ct*16+(lane&15)][kb*32+(lane>>4)*8+j]
__device__ inline void wfrag_build(int idx, int KB, const float* wl,
                                   const float* wr, _Float16* wf) {
  int j = idx & 7;
  int lane = (idx >> 3) & 63;
  int kb = (idx >> 9) % KB;
  int ct = (idx >> 9) / KB;
  int c = ct * 16 + (lane & 15);
  int k = kb * 32 + (lane >> 4) * 8 + j;
  float v = (k < 128) ? wl[c * 128 + k] : wr[c * 128 + (k - 128)];
  wf[idx] = (_Float16)v;
}

constexpr int CONVB = (N * 128 / 8 + 255) / 256;   // 3125 convert blocks
constexpr int MASKB = (N * 128) / (8 * 256);       // 3125 blocks per mask

__global__ __launch_bounds__(256) void setup_kernel(
    const float* __restrict__ x,
    const float* __restrict__ u1, const float* __restrict__ u2,
    const float* __restrict__ wl0, const float* __restrict__ wr0,
    const float* __restrict__ wl1, const float* __restrict__ wr1,
    const float* __restrict__ wl2, const float* __restrict__ wr2,
    _Float16* __restrict__ HA, _Float16* __restrict__ wf0,
    _Float16* __restrict__ wf1, _Float16* __restrict__ wfZ,
    unsigned* __restrict__ mk1, unsigned* __restrict__ mk2,
    int* __restrict__ bcur) {
  const int b = blockIdx.x;
  const int t = threadIdx.x;
  if (b < CONVB) {
    int i = b * 256 + t;                  // one thread per 8 elems
    if (i < N * 128 / 8) {
      float4 a = ((const float4*)x)[i * 2];
      float4 c = ((const float4*)x)[i * 2 + 1];
      f16x8 v;
      v[0] = (_Float16)a.x; v[1] = (_Float16)a.y; v[2] = (_Float16)a.z; v[3] = (_Float16)a.w;
      v[4] = (_Float16)c.x; v[5] = (_Float16)c.y; v[6] = (_Float16)c.z; v[7] = (_Float16)c.w;
      ((f16x8*)HA)[i] = v;
    }
  } else if (b < CONVB + 128) {           // wf0: [wl0|wr0], K=256 (32768 = 128 blk)
    wfrag_build((b - CONVB) * 256 + t, 8, wl0, wr0, wf0);
  } else if (b < CONVB + 256) {           // wf1: [wl1|wr1]
    wfrag_build((b - CONVB - 128) * 256 + t, 8, wl1, wr1, wf1);
  } else if (b < CONVB + 320) {           // wfZ: 8ct*4kb*512 = 16384 = 64 blocks
    int idx = (b - CONVB - 256) * 256 + t;
    int j = idx & 7;
    int lane = (idx >> 3) & 63;
    int kb = (idx >> 9) & 3;
    int ct = idx >> 11;                   // 0..7
    int c = ct * 16 + (lane & 15);
    int k = kb * 32 + (lane >> 4) * 8 + j;
    float v = (c < 64) ? wl2[c * 128 + k] : wr2[(c - 64) * 128 + k];
    wfZ[idx] = (_Float16)v;
  } else if (b < CONVB + 320 + 2 * MASKB) {   // bit-pack dropout masks
    int mb = b - (CONVB + 320);
    const float* Us = (mb < MASKB) ? u1 : u2;
    unsigned* MKs = (mb < MASKB) ? mk1 : mk2;
    int bb = (mb < MASKB) ? mb : (mb - MASKB);
#pragma unroll
    for (int k = 0; k < 8; ++k) {
      int i = (bb * 8 + k) * 256 + t;     // elem index; wave covers 64 consec
      float uv = Us[i];
      unsigned long long m = __ballot(uv >= 0.3f);
      int lt = t & 63;
      if (lt == 0) MKs[i >> 5] = (unsigned)m;
      else if (lt == 32) MKs[i >> 5] = (unsigned)(m >> 32);
    }
  } else {                                // bcur init (1 block)
    if (t < NBUCK) bcur[t] = t * SLOT;
  }
}

// ---------------- fused layer: gather-mean -> LDS frags -> MFMA GEMM -------
// One block = 32 output rows. Phase 1a: stage own H rows into frag-ordered
// LDS (kb 4-7). Phase 1b: half-wave-per-node gather-mean (plain loads,
// 16-wide batches, int4 edge-index loads) into frag-ordered LDS (kb 0-3).
// Phase 2: 4 waves x 32 cols GEMM, A from LDS, B frags from global
// (L2-resident 64 KB table). Epilogue: +bias, relu, bit-mask dropout, store.
__global__ __launch_bounds__(256, 4) void fused_layer_kernel(
    const _Float16* __restrict__ H, const int* __restrict__ offs,
    const int* __restrict__ deg, const int* __restrict__ elist,
    const _Float16* __restrict__ Wf, const float* __restrict__ bias,
    const unsigned* __restrict__ MK, _Float16* __restrict__ outp) {
  __shared__ __align__(16) _Float16 Af[2][8][64][8];   // [h][kb][lane][j] 16 KB
  const int t = threadIdx.x;
  const int rowbase = blockIdx.x * 32;

  // phase 1a: own H rows -> Af[.][4..7][.][.]  (512 octets, 2 per thread)
#pragma unroll
  for (int m2 = 0; m2 < 2; ++m2) {
    int m = t * 2 + m2;
    int r = m >> 4, o = m & 15;           // r: 0..31 row, o: 0..15 octet
    int row = min(rowbase + r, N - 1);    // clamp feeds only discarded rows
    f16x8 v = *(const f16x8*)(H + (size_t)row * 128 + o * 8);
    *(f16x8*)&Af[r >> 4][4 + (o >> 2)][(o & 3) * 16 + (r & 15)][0] = v;
  }

  // phase 1b: gather-mean -> Af[.][0..3][.][.]; half-wave (32 lanes) per node
  {
    const int hw = t >> 5;                // 0..7
    const int ll = t & 31;                // cols 4*ll .. 4*ll+3
    const int kb = ll >> 3, q = (ll >> 1) & 3, j = (ll & 1) * 4;
#pragma unroll 1
    for (int i = 0; i < 4; ++i) {
      int r = hw * 4 + i;
      int node = rowbase + r;
      float a0 = 0.f, a1 = 0.f, a2 = 0.f, a3 = 0.f;
      int d = 0;
      if (node < N) {
        const int e0 = offs[node];        // e0 % 4 == 0 (padded scan)
        d = deg[node];
        const int e1 = e0 + d;
        int e = e0;
        for (; e + 16 <= e1; e += 16) {
          int4 q0 = *(const int4*)(elist + e);
          int4 q1 = *(const int4*)(elist + e + 4);
          int4 q2 = *(const int4*)(elist + e + 8);
          int4 q3 = *(const int4*)(elist + e + 12);
          int s[16] = {q0.x, q0.y, q0.z, q0.w, q1.x, q1.y, q1.z, q1.w,
                       q2.x, q2.y, q2.z, q2.w, q3.x, q3.y, q3.z, q3.w};
          f16x4 v[16];
#pragma unroll
          for (int u = 0; u < 16; ++u)
            v[u] = *(const f16x4*)(H + (size_t)s[u] * 128 + ll * 4);
#pragma unroll
          for (int u = 0; u < 16; ++u) {
            a0 += (float)v[u][0]; a1 += (float)v[u][1];
            a2 += (float)v[u][2]; a3 += (float)v[u][3];
          }
        }
        for (; e + 4 <= e1; e += 4) {
          int4 qq4 = *(const int4*)(elist + e);
          int s[4] = {qq4.x, qq4.y, qq4.z, qq4.w};
          f16x4 v[4];
#pragma unroll
          for (int u = 0; u < 4; ++u)
            v[u] = *(const f16x4*)(H + (size_t)s[u] * 128 + ll * 4);
#pragma unroll
          for (int u = 0; u < 4; ++u) {
            a0 += (float)v[u][0]; a1 += (float)v[u][1];
            a2 += (float)v[u][2]; a3 += (float)v[u][3];
          }
        }
        for (; e < e1; ++e) {
          f16x4 v = *(const f16x4*)(H + (size_t)elist[e] * 128 + ll * 4);
          a0 += (float)v[0]; a1 += (float)v[1];
          a2 += (float)v[2]; a3 += (float)v[3];
        }
      }
      float inv = 1.0f / (float)max(d, 1);
      f16x4 o;
      o[0] = (_Float16)(a0 * inv); o[1] = (_Float16)(a1 * inv);
      o[2] = (_Float16)(a2 * inv); o[3] = (_Float16)(a3 * inv);
      *(f16x4*)&Af[r >> 4][kb][q * 16 + (r & 15)][j] = o;
    }
  }
  __syncthreads();

  // phase 2: GEMM. Wave w covers cols w*32..w*32+31.
  const int lane = t & 63;
  const int w = t >> 6;
  const int n16 = lane & 15;
  const int qq = lane >> 4;
  const int colbase = w * 32;

  f32x4 acc[2][2];
#pragma unroll
  for (int h = 0; h < 2; ++h)
#pragma unroll
    for (int ct = 0; ct < 2; ++ct) acc[h][ct] = (f32x4){0.f, 0.f, 0.f, 0.f};

#pragma unroll
  for (int kb = 0; kb < 8; ++kb) {
    f16x8 a0 = *(const f16x8*)&Af[0][kb][lane][0];
    f16x8 a1 = *(const f16x8*)&Af[1][kb][lane][0];
#pragma unroll
    for (int ct = 0; ct < 2; ++ct) {
      const int ctg = w * 2 + ct;
      f16x8 b = *(const f16x8*)(Wf + ((size_t)(ctg * 8 + kb) * 64 + lane) * 8);
      acc[0][ct] = __builtin_amdgcn_mfma_f32_16x16x32_f16(a0, b, acc[0][ct], 0, 0, 0);
      acc[1][ct] = __builtin_amdgcn_mfma_f32_16x16x32_f16(a1, b, acc[1][ct], 0, 0, 0);
    }
  }

  // C/D layout: col = lane&15, row = (lane>>4)*4 + reg
  // dropout bit for (row,col): MK[row*4 + w] bit (ct*16+n16)
#pragma unroll
  for (int h = 0; h < 2; ++h) {
#pragma unroll
    for (int r = 0; r < 4; ++r) {
      int row = rowbase + h * 16 + qq * 4 + r;
      if (row < N) {
        unsigned mw = MK[(size_t)row * 4 + w];
#pragma unroll
        for (int ct = 0; ct < 2; ++ct) {
          const int col = colbase + ct * 16 + n16;
          float v = fmaxf(acc[h][ct][r] + bias[col], 0.f);
          v = ((mw >> (ct * 16 + n16)) & 1u) ? v * (1.0f / 0.7f) : 0.0f;
          outp[(size_t)row * 128 + col] = (_Float16)v;
        }
      }
    }
  }
}

// ---------------- gather64 + final add: out = F + mean(Y2[nbrs]) ----------
// Half-wave (32 lanes x f16x2) per node; plain loads; writes f32 d_out.
__global__ __launch_bounds__(256) void gather64_add_kernel(
    const _Float16* __restrict__ Y2, const float* __restrict__ F,
    const int* __restrict__ offs, const int* __restrict__ deg,
    const int* __restrict__ elist, float* __restrict__ out) {
  int node = blockIdx.x * 8 + (threadIdx.x >> 5);
  if (node >= N) return;
  int l = threadIdx.x & 31;
  const int e0 = offs[node];              // e0 % 4 == 0
  const int d = deg[node];
  const int e1 = e0 + d;
  float a0 = 0.f, a1 = 0.f;
  int e = e0;
  for (; e + 16 <= e1; e += 16) {
    int4 q0 = *(const int4*)(elist + e);
    int4 q1 = *(const int4*)(elist + e + 4);
    int4 q2 = *(const int4*)(elist + e + 8);
    int4 q3 = *(const int4*)(elist + e + 12);
    int s[16] = {q0.x, q0.y, q0.z, q0.w, q1.x, q1.y, q1.z, q1.w,
                 q2.x, q2.y, q2.z, q2.w, q3.x, q3.y, q3.z, q3.w};
    f16x2 v[16];
#pragma unroll
    for (int u = 0; u < 16; ++u)
      v[u] = *(const f16x2*)(Y2 + (size_t)s[u] * 64 + l * 2);
#pragma unroll
    for (int u = 0; u < 16; ++u) { a0 += (float)v[u][0]; a1 += (float)v[u][1]; }
  }
  for (; e + 4 <= e1; e += 4) {
    int4 q = *(const int4*)(elist + e);
    int s[4] = {q.x, q.y, q.z, q.w};
    f16x2 v[4];
#pragma unroll
    for (int u = 0; u < 4; ++u)
      v[u] = *(const f16x2*)(Y2 + (size_t)s[u] * 64 + l * 2);
#pragma unroll
    for (int u = 0; u < 4; ++u) { a0 += (float)v[u][0]; a1 += (float)v[u][1]; }
  }
  for (; e < e1; ++e) {
    f16x2 v = *(const f16x2*)(Y2 + (size_t)elist[e] * 64 + l * 2);
    a0 += (float)v[0]; a1 += (float)v[1];
  }
  float inv = 1.0f / (float)max(d, 1);
  float2 f = ((const float2*)(F + (size_t)node * 64))[l];
  float2 o;
  o.x = f.x + a0 * inv;
  o.y = f.y + a1 * inv;
  ((float2*)(out + (size_t)node * 64))[l] = o;
}

// ---------------- layer-2 Z GEMM: cols 0-63 -> Y2=H@wl2^T (f16);
//                  cols 64-127 -> F=H@wr2^T+bl2 (f32). K=128.
__global__ __launch_bounds__(256, 4) void mfma_gemmZ_kernel(
    const _Float16* __restrict__ Hh, const _Float16* __restrict__ Wf,
    const float* __restrict__ bl2, _Float16* __restrict__ Y2,
    float* __restrict__ F) {
  const int lane = threadIdx.x & 63;
  const int w = threadIdx.x >> 6;
  const int n16 = lane & 15;
  const int q = lane >> 4;
  const int rowbase = blockIdx.x * 32;
  const int colbase = w * 32;

  f32x4 acc[2][2];
#pragma unroll
  for (int h = 0; h < 2; ++h)
#pragma unroll
    for (int ct = 0; ct < 2; ++ct) acc[h][ct] = (f32x4){0.f, 0.f, 0.f, 0.f};

  int ar0 = min(rowbase + n16, N - 1);
  int ar1 = min(rowbase + 16 + n16, N - 1);
  const _Float16* pH0 = Hh + (size_t)ar0 * 128 + q * 8;
  const _Float16* pH1 = Hh + (size_t)ar1 * 128 + q * 8;

#pragma unroll
  for (int kb = 0; kb < 4; ++kb) {
    const int ko = kb * 32;
    f16x8 a0 = *(const f16x8*)(pH0 + ko);
    f16x8 a1 = *(const f16x8*)(pH1 + ko);
#pragma unroll
    for (int ct = 0; ct < 2; ++ct) {
      const int ctg = w * 2 + ct;
      f16x8 b = *(const f16x8*)(Wf + ((size_t)(ctg * 4 + kb) * 64 + lane) * 8);
      acc[0][ct] = __builtin_amdgcn_mfma_f32_16x16x32_f16(a0, b, acc[0][ct], 0, 0, 0);
      acc[1][ct] = __builtin_amdgcn_mfma_f32_16x16x32_f16(a1, b, acc[1][ct], 0, 0, 0);
    }
  }

#pragma unroll
  for (int h = 0; h < 2; ++h) {
#pragma unroll
    for (int ct = 0; ct < 2; ++ct) {
      const int col = colbase + ct * 16 + n16;
#pragma unroll
      for (int r = 0; r < 4; ++r) {
        int row = rowbase + h * 16 + q * 4 + r;
        if (row < N) {
          float v = acc[h][ct][r];
          if (col < 64) Y2[(size_t)row * 64 + col] = (_Float16)v;
          else F[(size_t)row * 64 + (col - 64)] = v + bl2[col - 64];
        }
      }
    }
  }
}

extern "C" void kernel_launch(void* const* d_in, const int* in_sizes, int n_in,
                              void* d_out, int out_size, void* d_ws, size_t ws_size,
                              hipStream_t stream) {
  const float* x   = (const float*)d_in[0];
  const float* u1  = (const float*)d_in[1];
  const float* u2  = (const float*)d_in[2];
  const float* wl0 = (const float*)d_in[3];
  const float* bl0 = (const float*)d_in[4];
  const float* wr0 = (const float*)d_in[5];
  const float* wl1 = (const float*)d_in[6];
  const float* bl1 = (const float*)d_in[7];
  const float* wr1 = (const float*)d_in[8];
  const float* wl2 = (const float*)d_in[9];
  const float* bl2 = (const float*)d_in[10];
  const float* wr2 = (const float*)d_in[11];
  const int* edge  = (const int*)d_in[12];
  const int* src = edge;
  const int* dst = edge + E;

  // workspace layout
  _Float16* HA  = (_Float16*)d_ws;                 // N x 128 f16
  _Float16* HB  = HA + (size_t)N * 128;            // N x 128 f16
  _Float16* M16 = HB + (size_t)N * 128;            // N x 128 f16 (Y2 in layer 2)
  float* F      = (float*)(M16 + (size_t)N * 128); // N x 64 f32
  int* offs     = (int*)(F + (size_t)N * 64);      // N
  int* deg      = offs + N;                        // N
  int* elist    = deg + N;                         // NBUCK*SLOT (padded)
  unsigned* T   = (unsigned*)(elist + NBUCK * SLOT);
  int* bcur     = (int*)(T + NBUCK * SLOT);        // NBUCK
  uintptr_t p = (uintptr_t)(bcur + NBUCK);
  p = (p + 15) & ~(uintptr_t)15;
  _Float16* wf0 = (_Float16*)p;                    // 8*8*512
  _Float16* wf1 = wf0 + 8 * 8 * 512;
  _Float16* wfZ = wf1 + 8 * 8 * 512;               // 8*4*512
  unsigned* mk1 = (unsigned*)(wfZ + 8 * 4 * 512);  // N*4 u32 (bit mask)
  unsigned* mk2 = mk1 + (size_t)N * 4;             // N*4 u32

  // 1) setup: convert + 3 wfrag tables + dropout bit-masks + bcur init
  setup_kernel<<<CONVB + 320 + 2 * MASKB + 1, 256, 0, stream>>>(
      x, u1, u2, wl0, wr0, wl1, wr1, wl2, wr2, HA, wf0, wf1, wfZ, mk1, mk2,
      bcur);
  // 2-3) CSR build
  bucket_scatter_kernel<<<NEB, 256, 0, stream>>>(src, dst, bcur, T);
  bucket_place_kernel<<<NBUCK, 256, 0, stream>>>(T, bcur, offs, deg, elist);

  const int GM   = (N + 31) / 32;      // 32 rows/block
  const int GG64 = (N + 7) / 8;        // half-wave per node

  // ---- Layer 0 (fused gather+GEMM) ----
  fused_layer_kernel<<<GM, 256, 0, stream>>>(HA, offs, deg, elist, wf0, bl0, mk1, HB);
  // ---- Layer 1 (fused gather+GEMM) ----
  fused_layer_kernel<<<GM, 256, 0, stream>>>(HB, offs, deg, elist, wf1, bl1, mk2, HA);
  // ---- Layer 2 ----
  mfma_gemmZ_kernel<<<GM, 256, 0, stream>>>(HA, wfZ, bl2, M16, F);
  gather64_add_kernel<<<GG64, 256, 0, stream>>>(M16, F, offs, deg, elist,
                                                (float*)d_out);
}

// Round 4
// 280.533 us; speedup vs baseline: 1.2789x; 1.1199x over previous
//
#include <hip/hip_runtime.h>

// GraphSAGE 3-layer forward, MI355X. Round 13:
//   R12 post-mortem: bit-mask dropout helped the fused layer (FETCH 94->82MB)
//   but building masks in setup cost ~26us vs ~3us saved. Fused layer at
//   occupancy 39% with grid 1563 = 6.1 blocks/CU: gather concurrency is
//   GRID-capped, not fabric-capped. Changes:
//   - fused layer 32->16 rows/block: grid 3125, LDS 8KB, lb(256,8).
//     50000%16==0 -> no row-bound checks at all. Shorter serial edge chains.
//   - mask build moved from setup into bucket_place launch (196-block kernel
//     on 256 CUs; masks stream in the idle CUs).
//   - everything else = R12 (4-aligned elist, int4 index loads, mask epilogue).

constexpr int N = 50000;
constexpr int E = 800000;
constexpr int NBUCK = (N + 255) / 256;    // 196 dst-buckets (256 nodes each)
constexpr int CE = 2048;                  // edges per scatter chunk
constexpr int NEB = (E + CE - 1) / CE;    // 391
constexpr int SLOT = 5632;                // padded slab (exp 4096 + sigma + 4-align pad)
static_assert(N <= 65536, "u16 packing");
static_assert(N % 16 == 0, "16-row blocks need no bounds checks");

typedef _Float16 f16x8 __attribute__((ext_vector_type(8)));
typedef _Float16 f16x4 __attribute__((ext_vector_type(4)));
typedef _Float16 f16x2 __attribute__((ext_vector_type(2)));
typedef float f32x4 __attribute__((ext_vector_type(4)));

// ---------------- CSR build (padded buckets; no global hist/scan) ----------

// Phase A: LDS counting sort of a CE-edge chunk by dst>>8; append grouped
// runs of packed (dst<<16|src) into each bucket's padded slab of T.
__global__ __launch_bounds__(256) void bucket_scatter_kernel(
    const int* __restrict__ src, const int* __restrict__ dst,
    int* __restrict__ bcur, unsigned* __restrict__ T) {
  __shared__ unsigned sorted[CE];
  __shared__ int hist[256], scan[256], excl[256], lcur[256], gbase[256];
  const int t = threadIdx.x;
  const int e0 = blockIdx.x * CE;
  const int nval = min(CE, E - e0);
  hist[t] = 0;
  __syncthreads();
  for (int i = t; i < nval; i += 256) atomicAdd(&hist[dst[e0 + i] >> 8], 1);
  __syncthreads();
  const int h = hist[t];
  scan[t] = h;
  __syncthreads();
  for (int off = 1; off < 256; off <<= 1) {
    int u = (t >= off) ? scan[t - off] : 0;
    __syncthreads();
    scan[t] += u;
    __syncthreads();
  }
  excl[t] = scan[t] - h;
  lcur[t] = scan[t] - h;
  gbase[t] = (t < NBUCK && h > 0) ? atomicAdd(&bcur[t], h) : 0;
  __syncthreads();
  for (int i = t; i < nval; i += 256) {
    int e = e0 + i;
    int d = dst[e];
    int p = atomicAdd(&lcur[d >> 8], 1);
    sorted[p] = ((unsigned)d << 16) | (unsigned)src[e];
  }
  __syncthreads();
  for (int i = t; i < nval; i += 256) {
    unsigned pk = sorted[i];
    int b = pk >> 24;                     // == dst>>8
    T[gbase[b] + (i - excl[b])] = pk;
  }
}

constexpr int MASKB = (N * 128) / (8 * 256);       // 3125 blocks per mask

// Phase B: blocks [0,NBUCK): per-bucket offsets/degrees (4-ALIGNED segment
// scan) + edge placement. Blocks [NBUCK, NBUCK+2*MASKB): bit-pack dropout
// masks (streams on otherwise-idle CUs; masks needed only by later layers).
__global__ __launch_bounds__(256) void bucket_place_kernel(
    const unsigned* __restrict__ T, const int* __restrict__ bcur,
    const float* __restrict__ u1, const float* __restrict__ u2,
    unsigned* __restrict__ mk1, unsigned* __restrict__ mk2,
    int* __restrict__ offs, int* __restrict__ deg, int* __restrict__ elist) {
  __shared__ int dcnt[256], s[256], ncur[256];
  const int t = threadIdx.x;
  const int b = blockIdx.x;
  if (b >= NBUCK) {                       // ---- mask branch ----
    int mb = b - NBUCK;
    const float* Us = (mb < MASKB) ? u1 : u2;
    unsigned* MKs = (mb < MASKB) ? mk1 : mk2;
    int bb = (mb < MASKB) ? mb : (mb - MASKB);
#pragma unroll
    for (int k = 0; k < 8; ++k) {
      int i = (bb * 8 + k) * 256 + t;     // wave covers 64 consecutive elems
      unsigned long long m = __ballot(Us[i] >= 0.3f);
      int lt = t & 63;
      if (lt == 0) MKs[i >> 5] = (unsigned)m;
      else if (lt == 32) MKs[i >> 5] = (unsigned)(m >> 32);
    }
    return;
  }
  const int lo = b * SLOT;
  const int hi = bcur[b];                 // lo + edges-in-bucket
  dcnt[t] = 0;
  __syncthreads();
  for (int i = lo + t; i < hi; i += 256) atomicAdd(&dcnt[(T[i] >> 16) & 255], 1);
  __syncthreads();
  const int v = dcnt[t];
  const int pv = (v + 3) & ~3;            // 4-aligned segment length
  s[t] = pv;
  __syncthreads();
  for (int off = 1; off < 256; off <<= 1) {
    int u = (t >= off) ? s[t - off] : 0;
    __syncthreads();
    s[t] += u;
    __syncthreads();
  }
  const int base = lo + s[t] - pv;        // within-bucket exclusive + slab base
  const int node = b * 256 + t;
  if (node < N) { offs[node] = base; deg[node] = v; }
  ncur[t] = base;
  __syncthreads();
  for (int i = lo + t; i < hi; i += 256) {
    unsigned pk = T[i];
    int pos = atomicAdd(&ncur[(pk >> 16) & 255], 1);
    elist[pos] = (int)(pk & 0xffffu);
  }
}

// ---------------- fused setup: convert + wfrag tables + bcur init ----------
// Wf[((ct*KB+kb)*64+lane)*8+j] = Wcat[ct*16+(lane&15)][kb*32+(lane>>4)*8+j]
__device__ inline void wfrag_build(int idx, int KB, const float* wl,
                                   const float* wr, _Float16* wf) {
  int j = idx & 7;
  int lane = (idx >> 3) & 63;
  int kb = (idx >> 9) % KB;
  int ct = (idx >> 9) / KB;
  int c = ct * 16 + (lane & 15);
  int k = kb * 32 + (lane >> 4) * 8 + j;
  float v = (k < 128) ? wl[c * 128 + k] : wr[c * 128 + (k - 128)];
  wf[idx] = (_Float16)v;
}

constexpr int CONVB = (N * 128 / 8 + 255) / 256;   // 3125 convert blocks

__global__ __launch_bounds__(256) void setup_kernel(
    const float* __restrict__ x,
    const float* __restrict__ wl0, const float* __restrict__ wr0,
    const float* __restrict__ wl1, const float* __restrict__ wr1,
    const float* __restrict__ wl2, const float* __restrict__ wr2,
    _Float16* __restrict__ HA, _Float16* __restrict__ wf0,
    _Float16* __restrict__ wf1, _Float16* __restrict__ wfZ,
    int* __restrict__ bcur) {
  const int b = blockIdx.x;
  const int t = threadIdx.x;
  if (b < CONVB) {
    int i = b * 256 + t;                  // one thread per 8 elems
    if (i < N * 128 / 8) {
      float4 a = ((const float4*)x)[i * 2];
      float4 c = ((const float4*)x)[i * 2 + 1];
      f16x8 v;
      v[0] = (_Float16)a.x; v[1] = (_Float16)a.y; v[2] = (_Float16)a.z; v[3] = (_Float16)a.w;
      v[4] = (_Float16)c.x; v[5] = (_Float16)c.y; v[6] = (_Float16)c.z; v[7] = (_Float16)c.w;
      ((f16x8*)HA)[i] = v;
    }
  } else if (b < CONVB + 128) {           // wf0: [wl0|wr0], K=256 (32768 = 128 blk)
    wfrag_build((b - CONVB) * 256 + t, 8, wl0, wr0, wf0);
  } else if (b < CONVB + 256) {           // wf1: [wl1|wr1]
    wfrag_build((b - CONVB - 128) * 256 + t, 8, wl1, wr1, wf1);
  } else if (b < CONVB + 320) {           // wfZ: 8ct*4kb*512 = 16384 = 64 blocks
    int idx = (b - CONVB - 256) * 256 + t;
    int j = idx & 7;
    int lane = (idx >> 3) & 63;
    int kb = (idx >> 9) & 3;
    int ct = idx >> 11;                   // 0..7
    int c = ct * 16 + (lane & 15);
    int k = kb * 32 + (lane >> 4) * 8 + j;
    float v = (c < 64) ? wl2[c * 128 + k] : wr2[(c - 64) * 128 + k];
    wfZ[idx] = (_Float16)v;
  } else {                                // bcur init (1 block)
    if (t < NBUCK) bcur[t] = t * SLOT;
  }
}

// ---------------- fused layer: gather-mean -> LDS frags -> MFMA GEMM -------
// One block = 16 output rows (N%16==0: no bounds checks). Phase 1a: stage own
// H rows into frag-ordered LDS (kb 4-7). Phase 1b: half-wave-per-node
// gather-mean (2 nodes per half-wave) into frag-ordered LDS (kb 0-3).
// Phase 2: 4 waves x 32 cols GEMM, A from LDS, B frags from global
// (L2-resident 64 KB table). Epilogue: +bias, relu, bit-mask dropout, store.
__global__ __launch_bounds__(256, 8) void fused_layer_kernel(
    const _Float16* __restrict__ H, const int* __restrict__ offs,
    const int* __restrict__ deg, const int* __restrict__ elist,
    const _Float16* __restrict__ Wf, const float* __restrict__ bias,
    const unsigned* __restrict__ MK, _Float16* __restrict__ outp) {
  __shared__ __align__(16) _Float16 Af[8][64][8];      // [kb][lane][j] 8 KB
  const int t = threadIdx.x;
  const int rowbase = blockIdx.x * 16;

  // phase 1a: own H rows -> Af[4..7][.][.]  (256 octets, 1 per thread)
  {
    int r = t >> 4, o = t & 15;           // r: 0..15 row, o: 0..15 octet
    f16x8 v = *(const f16x8*)(H + (size_t)(rowbase + r) * 128 + o * 8);
    *(f16x8*)&Af[4 + (o >> 2)][(o & 3) * 16 + r][0] = v;
  }

  // phase 1b: gather-mean -> Af[0..3][.][.]; half-wave (32 lanes) per node
  {
    const int hw = t >> 5;                // 0..7
    const int ll = t & 31;                // cols 4*ll .. 4*ll+3
    const int kb = ll >> 3, q = (ll >> 1) & 3, j = (ll & 1) * 4;
#pragma unroll 1
    for (int i = 0; i < 2; ++i) {
      int r = hw * 2 + i;
      int node = rowbase + r;
      float a0 = 0.f, a1 = 0.f, a2 = 0.f, a3 = 0.f;
      const int e0 = offs[node];          // e0 % 4 == 0 (padded scan)
      const int d = deg[node];
      const int e1 = e0 + d;
      int e = e0;
      for (; e + 16 <= e1; e += 16) {
        int4 q0 = *(const int4*)(elist + e);
        int4 q1 = *(const int4*)(elist + e + 4);
        int4 q2 = *(const int4*)(elist + e + 8);
        int4 q3 = *(const int4*)(elist + e + 12);
        int s[16] = {q0.x, q0.y, q0.z, q0.w, q1.x, q1.y, q1.z, q1.w,
                     q2.x, q2.y, q2.z, q2.w, q3.x, q3.y, q3.z, q3.w};
        f16x4 v[16];
#pragma unroll
        for (int u = 0; u < 16; ++u)
          v[u] = *(const f16x4*)(H + (size_t)s[u] * 128 + ll * 4);
#pragma unroll
        for (int u = 0; u < 16; ++u) {
          a0 += (float)v[u][0]; a1 += (float)v[u][1];
          a2 += (float)v[u][2]; a3 += (float)v[u][3];
        }
      }
      for (; e + 4 <= e1; e += 4) {
        int4 qq4 = *(const int4*)(elist + e);
        int s[4] = {qq4.x, qq4.y, qq4.z, qq4.w};
        f16x4 v[4];
#pragma unroll
        for (int u = 0; u < 4; ++u)
          v[u] = *(const f16x4*)(H + (size_t)s[u] * 128 + ll * 4);
#pragma unroll
        for (int u = 0; u < 4; ++u) {
          a0 += (float)v[u][0]; a1 += (float)v[u][1];
          a2 += (float)v[u][2]; a3 += (float)v[u][3];
        }
      }
      for (; e < e1; ++e) {
        f16x4 v = *(const f16x4*)(H + (size_t)elist[e] * 128 + ll * 4);
        a0 += (float)v[0]; a1 += (float)v[1];
        a2 += (float)v[2]; a3 += (float)v[3];
      }
      float inv = 1.0f / (float)max(d, 1);
      f16x4 o;
      o[0] = (_Float16)(a0 * inv); o[1] = (_Float16)(a1 * inv);
      o[2] = (_Float16)(a2 * inv); o[3] = (_Float16)(a3 * inv);
      *(f16x4*)&Af[kb][q * 16 + r][j] = o;
    }
  }
  __syncthreads();

  // phase 2: GEMM. Wave w covers cols w*32..w*32+31; 16 rows.
  const int lane = t & 63;
  const int w = t >> 6;
  const int n16 = lane & 15;
  const int qq = lane >> 4;
  const int colbase = w * 32;

  f32x4 acc[2];
  acc[0] = (f32x4){0.f, 0.f, 0.f, 0.f};
  acc[1] = (f32x4){0.f, 0.f, 0.f, 0.f};

#pragma unroll
  for (int kb = 0; kb < 8; ++kb) {
    f16x8 a = *(const f16x8*)&Af[kb][lane][0];
#pragma unroll
    for (int ct = 0; ct < 2; ++ct) {
      const int ctg = w * 2 + ct;
      f16x8 b = *(const f16x8*)(Wf + ((size_t)(ctg * 8 + kb) * 64 + lane) * 8);
      acc[ct] = __builtin_amdgcn_mfma_f32_16x16x32_f16(a, b, acc[ct], 0, 0, 0);
    }
  }

  // C/D layout: col = lane&15, row = (lane>>4)*4 + reg
  // dropout bit for (row,col): MK[row*4 + w] bit (ct*16+n16)
#pragma unroll
  for (int r = 0; r < 4; ++r) {
    int row = rowbase + qq * 4 + r;
    unsigned mw = MK[(size_t)row * 4 + w];
#pragma unroll
    for (int ct = 0; ct < 2; ++ct) {
      const int col = colbase + ct * 16 + n16;
      float v = fmaxf(acc[ct][r] + bias[col], 0.f);
      v = ((mw >> (ct * 16 + n16)) & 1u) ? v * (1.0f / 0.7f) : 0.0f;
      outp[(size_t)row * 128 + col] = (_Float16)v;
    }
  }
}

// ---------------- gather64 + final add: out = F + mean(Y2[nbrs]) ----------
// Half-wave (32 lanes x f16x2) per node; plain loads; writes f32 d_out.
__global__ __launch_bounds__(256) void gather64_add_kernel(
    const _Float16* __restrict__ Y2, const float* __restrict__ F,
    const int* __restrict__ offs, const int* __restrict__ deg,
    const int* __restrict__ elist, float* __restrict__ out) {
  int node = blockIdx.x * 8 + (threadIdx.x >> 5);
  if (node >= N) return;
  int l = threadIdx.x & 31;
  const int e0 = offs[node];              // e0 % 4 == 0
  const int d = deg[node];
  const int e1 = e0 + d;
  float a0 = 0.f, a1 = 0.f;
  int e = e0;
  for (; e + 16 <= e1; e += 16) {
    int4 q0 = *(const int4*)(elist + e);
    int4 q1 = *(const int4*)(elist + e + 4);
    int4 q2 = *(const int4*)(elist + e + 8);
    int4 q3 = *(const int4*)(elist + e + 12);
    int s[16] = {q0.x, q0.y, q0.z, q0.w, q1.x, q1.y, q1.z, q1.w,
                 q2.x, q2.y, q2.z, q2.w, q3.x, q3.y, q3.z, q3.w};
    f16x2 v[16];
#pragma unroll
    for (int u = 0; u < 16; ++u)
      v[u] = *(const f16x2*)(Y2 + (size_t)s[u] * 64 + l * 2);
#pragma unroll
    for (int u = 0; u < 16; ++u) { a0 += (float)v[u][0]; a1 += (float)v[u][1]; }
  }
  for (; e + 4 <= e1; e += 4) {
    int4 q = *(const int4*)(elist + e);
    int s[4] = {q.x, q.y, q.z, q.w};
    f16x2 v[4];
#pragma unroll
    for (int u = 0; u < 4; ++u)
      v[u] = *(const f16x2*)(Y2 + (size_t)s[u] * 64 + l * 2);
#pragma unroll
    for (int u = 0; u < 4; ++u) { a0 += (float)v[u][0]; a1 += (float)v[u][1]; }
  }
  for (; e < e1; ++e) {
    f16x2 v = *(const f16x2*)(Y2 + (size_t)elist[e] * 64 + l * 2);
    a0 += (float)v[0]; a1 += (float)v[1];
  }
  float inv = 1.0f / (float)max(d, 1);
  float2 f = ((const float2*)(F + (size_t)node * 64))[l];
  float2 o;
  o.x = f.x + a0 * inv;
  o.y = f.y + a1 * inv;
  ((float2*)(out + (size_t)node * 64))[l] = o;
}

// ---------------- layer-2 Z GEMM: cols 0-63 -> Y2=H@wl2^T (f16);
//                  cols 64-127 -> F=H@wr2^T+bl2 (f32). K=128.
__global__ __launch_bounds__(256, 4) void mfma_gemmZ_kernel(
    const _Float16* __restrict__ Hh, const _Float16* __restrict__ Wf,
    const float* __restrict__ bl2, _Float16* __restrict__ Y2,
    float* __restrict__ F) {
  const int lane = threadIdx.x & 63;
  const int w = threadIdx.x >> 6;
  const int n16 = lane & 15;
  const int q = lane >> 4;
  const int rowbase = blockIdx.x * 32;
  const int colbase = w * 32;

  f32x4 acc[2][2];
#pragma unroll
  for (int h = 0; h < 2; ++h)
#pragma unroll
    for (int ct = 0; ct < 2; ++ct) acc[h][ct] = (f32x4){0.f, 0.f, 0.f, 0.f};

  int ar0 = min(rowbase + n16, N - 1);
  int ar1 = min(rowbase + 16 + n16, N - 1);
  const _Float16* pH0 = Hh + (size_t)ar0 * 128 + q * 8;
  const _Float16* pH1 = Hh + (size_t)ar1 * 128 + q * 8;

#pragma unroll
  for (int kb = 0; kb < 4; ++kb) {
    const int ko = kb * 32;
    f16x8 a0 = *(const f16x8*)(pH0 + ko);
    f16x8 a1 = *(const f16x8*)(pH1 + ko);
#pragma unroll
    for (int ct = 0; ct < 2; ++ct) {
      const int ctg = w * 2 + ct;
      f16x8 b = *(const f16x8*)(Wf + ((size_t)(ctg * 4 + kb) * 64 + lane) * 8);
      acc[0][ct] = __builtin_amdgcn_mfma_f32_16x16x32_f16(a0, b, acc[0][ct], 0, 0, 0);
      acc[1][ct] = __builtin_amdgcn_mfma_f32_16x16x32_f16(a1, b, acc[1][ct], 0, 0, 0);
    }
  }

#pragma unroll
  for (int h = 0; h < 2; ++h) {
#pragma unroll
    for (int ct = 0; ct < 2; ++ct) {
      const int col = colbase + ct * 16 + n16;
#pragma unroll
      for (int r = 0; r < 4; ++r) {
        int row = rowbase + h * 16 + q * 4 + r;
        if (row < N) {
          float v = acc[h][ct][r];
          if (col < 64) Y2[(size_t)row * 64 + col] = (_Float16)v;
          else F[(size_t)row * 64 + (col - 64)] = v + bl2[col - 64];
        }
      }
    }
  }
}

extern "C" void kernel_launch(void* const* d_in, const int* in_sizes, int n_in,
                              void* d_out, int out_size, void* d_ws, size_t ws_size,
                              hipStream_t stream) {
  const float* x   = (const float*)d_in[0];
  const float* u1  = (const float*)d_in[1];
  const float* u2  = (const float*)d_in[2];
  const float* wl0 = (const float*)d_in[3];
  const float* bl0 = (const float*)d_in[4];
  const float* wr0 = (const float*)d_in[5];
  const float* wl1 = (const float*)d_in[6];
  const float* bl1 = (const float*)d_in[7];
  const float* wr1 = (const float*)d_in[8];
  const float* wl2 = (const float*)d_in[9];
  const float* bl2 = (const float*)d_in[10];
  const float* wr2 = (const float*)d_in[11];
  const int* edge  = (const int*)d_in[12];
  const int* src = edge;
  const int* dst = edge + E;

  // workspace layout
  _Float16* HA  = (_Float16*)d_ws;                 // N x 128 f16
  _Float16* HB  = HA + (size_t)N * 128;            // N x 128 f16
  _Float16* M16 = HB + (size_t)N * 128;            // N x 128 f16 (Y2 in layer 2)
  float* F      = (float*)(M16 + (size_t)N * 128); // N x 64 f32
  int* offs     = (int*)(F + (size_t)N * 64);      // N
  int* deg      = offs + N;                        // N
  int* elist    = deg + N;                         // NBUCK*SLOT (padded)
  unsigned* T   = (unsigned*)(elist + NBUCK * SLOT);
  int* bcur     = (int*)(T + NBUCK * SLOT);        // NBUCK
  uintptr_t p = (uintptr_t)(bcur + NBUCK);
  p = (p + 15) & ~(uintptr_t)15;
  _Float16* wf0 = (_Float16*)p;                    // 8*8*512
  _Float16* wf1 = wf0 + 8 * 8 * 512;
  _Float16* wfZ = wf1 + 8 * 8 * 512;               // 8*4*512
  unsigned* mk1 = (unsigned*)(wfZ + 8 * 4 * 512);  // N*4 u32 (bit mask)
  unsigned* mk2 = mk1 + (size_t)N * 4;             // N*4 u32

  // 1) setup: convert + 3 wfrag tables + bcur init
  setup_kernel<<<CONVB + 321, 256, 0, stream>>>(
      x, wl0, wr0, wl1, wr1, wl2, wr2, HA, wf0, wf1, wfZ, bcur);
  // 2-3) CSR build (+ mask build streamed on idle CUs of the place launch)
  bucket_scatter_kernel<<<NEB, 256, 0, stream>>>(src, dst, bcur, T);
  bucket_place_kernel<<<NBUCK + 2 * MASKB, 256, 0, stream>>>(
      T, bcur, u1, u2, mk1, mk2, offs, deg, elist);

  const int GM16 = N / 16;             // 3125 fused-layer blocks
  const int GM   = (N + 31) / 32;      // 32 rows/block (gemmZ)
  const int GG64 = (N + 7) / 8;        // half-wave per node

  // ---- Layer 0 (fused gather+GEMM) ----
  fused_layer_kernel<<<GM16, 256, 0, stream>>>(HA, offs, deg, elist, wf0, bl0, mk1, HB);
  // ---- Layer 1 (fused gather+GEMM) ----
  fused_layer_kernel<<<GM16, 256, 0, stream>>>(HB, offs, deg, elist, wf1, bl1, mk2, HA);
  // ---- Layer 2 ----
  mfma_gemmZ_kernel<<<GM, 256, 0, stream>>>(HA, wfZ, bl2, M16, F);
  gather64_add_kernel<<<GG64, 256, 0, stream>>>(M16, F, offs, deg, elist,
                                                (float*)d_out);
}

// Round 5
// 268.216 us; speedup vs baseline: 1.3376x; 1.0459x over previous
//
#include <hip/hip_runtime.h>

// GraphSAGE 3-layer forward, MI355X. Round 14:
//   R13 worked (280.5us; fused 43.3us @ 57% occ). Now cut the ~194us of
//   non-fused-layer pipeline:
//   - fused_layerZ: layer-2 GEMM fused into layer-1 epilogue. h1 rows are
//     only consumed by Z=h1@[wl2|wr2]^T (gather runs on Y2 by linearity), so
//     h1 lives only in LDS: epilogue writes relu+dropout h1 -> Zf LDS tile,
//     sync, 8 MFMAs vs wfZ -> writes Y2(f16)+F(f32). Deletes mfma_gemmZ
//     dispatch AND the HA write+read round trip (25.6 MB).
//   - setup+scatter merged into one launch: bcur init via hipMemsetAsync
//     (bcur now holds counts; slab base added explicitly). Scatter's 391
//     LDS-heavy blocks overlap the BW-bound convert stream.
//   7 kernels -> 5 kernels + 1 memset.

constexpr int N = 50000;
constexpr int E = 800000;
constexpr int NBUCK = (N + 255) / 256;    // 196 dst-buckets (256 nodes each)
constexpr int CE = 2048;                  // edges per scatter chunk
constexpr int NEB = (E + CE - 1) / CE;    // 391
constexpr int SLOT = 5632;                // padded slab (exp 4096 + sigma + 4-align pad)
static_assert(N <= 65536, "u16 packing");
static_assert(N % 16 == 0, "16-row blocks need no bounds checks");

typedef _Float16 f16x8 __attribute__((ext_vector_type(8)));
typedef _Float16 f16x4 __attribute__((ext_vector_type(4)));
typedef _Float16 f16x2 __attribute__((ext_vector_type(2)));
typedef float f32x4 __attribute__((ext_vector_type(4)));

constexpr int CONVB = (N * 128 / 8 + 255) / 256;   // 3125 convert blocks
constexpr int MASKB = (N * 128) / (8 * 256);       // 3125 blocks per mask

// ---------------- merged setup + scatter ----------------------------------
// blocks [0, NEB): edge chunk counting-sort -> bucket slabs of T
// blocks [NEB, NEB+CONVB): x f32 -> HA f16 convert
// then 128 wf0, 128 wf1, 64 wfZ weight-fragment blocks.
// Wf[((ct*KB+kb)*64+lane)*8+j] = Wcat[ct*16+(lane&15)][kb*32+(lane>>4)*8+j]
__device__ inline void wfrag_build(int idx, int KB, const float* wl,
                                   const float* wr, _Float16* wf) {
  int j = idx & 7;
  int lane = (idx >> 3) & 63;
  int kb = (idx >> 9) % KB;
  int ct = (idx >> 9) / KB;
  int c = ct * 16 + (lane & 15);
  int k = kb * 32 + (lane >> 4) * 8 + j;
  float v = (k < 128) ? wl[c * 128 + k] : wr[c * 128 + (k - 128)];
  wf[idx] = (_Float16)v;
}

__global__ __launch_bounds__(256) void setup_scatter_kernel(
    const int* __restrict__ src, const int* __restrict__ dst,
    int* __restrict__ bcur, unsigned* __restrict__ T,
    const float* __restrict__ x,
    const float* __restrict__ wl0, const float* __restrict__ wr0,
    const float* __restrict__ wl1, const float* __restrict__ wr1,
    const float* __restrict__ wl2, const float* __restrict__ wr2,
    _Float16* __restrict__ HA, _Float16* __restrict__ wf0,
    _Float16* __restrict__ wf1, _Float16* __restrict__ wfZ) {
  __shared__ unsigned sorted[CE];
  __shared__ int hist[256], scan[256], excl[256], lcur[256], gbase[256];
  const int b = blockIdx.x;
  const int t = threadIdx.x;
  if (b < NEB) {                          // ---- scatter branch ----
    const int e0 = b * CE;
    const int nval = min(CE, E - e0);
    hist[t] = 0;
    __syncthreads();
    for (int i = t; i < nval; i += 256) atomicAdd(&hist[dst[e0 + i] >> 8], 1);
    __syncthreads();
    const int h = hist[t];
    scan[t] = h;
    __syncthreads();
    for (int off = 1; off < 256; off <<= 1) {
      int u = (t >= off) ? scan[t - off] : 0;
      __syncthreads();
      scan[t] += u;
      __syncthreads();
    }
    excl[t] = scan[t] - h;
    lcur[t] = scan[t] - h;
    gbase[t] = (t < NBUCK && h > 0) ? (t * SLOT + atomicAdd(&bcur[t], h)) : 0;
    __syncthreads();
    for (int i = t; i < nval; i += 256) {
      int e = e0 + i;
      int d = dst[e];
      int p = atomicAdd(&lcur[d >> 8], 1);
      sorted[p] = ((unsigned)d << 16) | (unsigned)src[e];
    }
    __syncthreads();
    for (int i = t; i < nval; i += 256) {
      unsigned pk = sorted[i];
      int bb = pk >> 24;                  // == dst>>8
      T[gbase[bb] + (i - excl[bb])] = pk;
    }
    return;
  }
  const int b2 = b - NEB;
  if (b2 < CONVB) {                       // ---- convert branch ----
    int i = b2 * 256 + t;                 // one thread per 8 elems
    if (i < N * 128 / 8) {
      float4 a = ((const float4*)x)[i * 2];
      float4 c = ((const float4*)x)[i * 2 + 1];
      f16x8 v;
      v[0] = (_Float16)a.x; v[1] = (_Float16)a.y; v[2] = (_Float16)a.z; v[3] = (_Float16)a.w;
      v[4] = (_Float16)c.x; v[5] = (_Float16)c.y; v[6] = (_Float16)c.z; v[7] = (_Float16)c.w;
      ((f16x8*)HA)[i] = v;
    }
  } else if (b2 < CONVB + 128) {          // wf0: [wl0|wr0], K=256
    wfrag_build((b2 - CONVB) * 256 + t, 8, wl0, wr0, wf0);
  } else if (b2 < CONVB + 256) {          // wf1: [wl1|wr1]
    wfrag_build((b2 - CONVB - 128) * 256 + t, 8, wl1, wr1, wf1);
  } else {                                // wfZ: 8ct*4kb*512 = 16384 = 64 blk
    int idx = (b2 - CONVB - 256) * 256 + t;
    int j = idx & 7;
    int lane = (idx >> 3) & 63;
    int kb = (idx >> 9) & 3;
    int ct = idx >> 11;                   // 0..7
    int c = ct * 16 + (lane & 15);
    int k = kb * 32 + (lane >> 4) * 8 + j;
    float v = (c < 64) ? wl2[c * 128 + k] : wr2[(c - 64) * 128 + k];
    wfZ[idx] = (_Float16)v;
  }
}

// Phase B: blocks [0,NBUCK): per-bucket offsets/degrees (4-ALIGNED segment
// scan) + edge placement. Blocks [NBUCK, NBUCK+2*MASKB): bit-pack dropout
// masks (streams on otherwise-idle CUs).
__global__ __launch_bounds__(256) void bucket_place_kernel(
    const unsigned* __restrict__ T, const int* __restrict__ bcur,
    const float* __restrict__ u1, const float* __restrict__ u2,
    unsigned* __restrict__ mk1, unsigned* __restrict__ mk2,
    int* __restrict__ offs, int* __restrict__ deg, int* __restrict__ elist) {
  __shared__ int dcnt[256], s[256], ncur[256];
  const int t = threadIdx.x;
  const int b = blockIdx.x;
  if (b >= NBUCK) {                       // ---- mask branch ----
    int mb = b - NBUCK;
    const float* Us = (mb < MASKB) ? u1 : u2;
    unsigned* MKs = (mb < MASKB) ? mk1 : mk2;
    int bb = (mb < MASKB) ? mb : (mb - MASKB);
#pragma unroll
    for (int k = 0; k < 8; ++k) {
      int i = (bb * 8 + k) * 256 + t;     // wave covers 64 consecutive elems
      unsigned long long m = __ballot(Us[i] >= 0.3f);
      int lt = t & 63;
      if (lt == 0) MKs[i >> 5] = (unsigned)m;
      else if (lt == 32) MKs[i >> 5] = (unsigned)(m >> 32);
    }
    return;
  }
  const int lo = b * SLOT;
  const int hi = lo + bcur[b];            // bcur holds per-bucket edge count
  dcnt[t] = 0;
  __syncthreads();
  for (int i = lo + t; i < hi; i += 256) atomicAdd(&dcnt[(T[i] >> 16) & 255], 1);
  __syncthreads();
  const int v = dcnt[t];
  const int pv = (v + 3) & ~3;            // 4-aligned segment length
  s[t] = pv;
  __syncthreads();
  for (int off = 1; off < 256; off <<= 1) {
    int u = (t >= off) ? s[t - off] : 0;
    __syncthreads();
    s[t] += u;
    __syncthreads();
  }
  const int base = lo + s[t] - pv;        // within-bucket exclusive + slab base
  const int node = b * 256 + t;
  if (node < N) { offs[node] = base; deg[node] = v; }
  ncur[t] = base;
  __syncthreads();
  for (int i = lo + t; i < hi; i += 256) {
    unsigned pk = T[i];
    int pos = atomicAdd(&ncur[(pk >> 16) & 255], 1);
    elist[pos] = (int)(pk & 0xffffu);
  }
}

// ---------------- fused layer 0: gather-mean -> LDS frags -> MFMA GEMM ----
// One block = 16 output rows (N%16==0: no bounds checks). Phase 1a: stage own
// H rows into frag-ordered LDS (kb 4-7). Phase 1b: half-wave-per-node
// gather-mean (2 nodes per half-wave) into frag-ordered LDS (kb 0-3).
// Phase 2: 4 waves x 32 cols GEMM. Epilogue: +bias, relu, mask dropout, store.
__global__ __launch_bounds__(256, 8) void fused_layer_kernel(
    const _Float16* __restrict__ H, const int* __restrict__ offs,
    const int* __restrict__ deg, const int* __restrict__ elist,
    const _Float16* __restrict__ Wf, const float* __restrict__ bias,
    const unsigned* __restrict__ MK, _Float16* __restrict__ outp) {
  __shared__ __align__(16) _Float16 Af[8][64][8];      // [kb][lane][j] 8 KB
  const int t = threadIdx.x;
  const int rowbase = blockIdx.x * 16;

  // phase 1a: own H rows -> Af[4..7][.][.]  (256 octets, 1 per thread)
  {
    int r = t >> 4, o = t & 15;           // r: 0..15 row, o: 0..15 octet
    f16x8 v = *(const f16x8*)(H + (size_t)(rowbase + r) * 128 + o * 8);
    *(f16x8*)&Af[4 + (o >> 2)][(o & 3) * 16 + r][0] = v;
  }

  // phase 1b: gather-mean -> Af[0..3][.][.]; half-wave (32 lanes) per node
  {
    const int hw = t >> 5;                // 0..7
    const int ll = t & 31;                // cols 4*ll .. 4*ll+3
    const int kb = ll >> 3, q = (ll >> 1) & 3, j = (ll & 1) * 4;
#pragma unroll 1
    for (int i = 0; i < 2; ++i) {
      int r = hw * 2 + i;
      int node = rowbase + r;
      float a0 = 0.f, a1 = 0.f, a2 = 0.f, a3 = 0.f;
      const int e0 = offs[node];          // e0 % 4 == 0 (padded scan)
      const int d = deg[node];
      const int e1 = e0 + d;
      int e = e0;
      for (; e + 16 <= e1; e += 16) {
        int4 q0 = *(const int4*)(elist + e);
        int4 q1 = *(const int4*)(elist + e + 4);
        int4 q2 = *(const int4*)(elist + e + 8);
        int4 q3 = *(const int4*)(elist + e + 12);
        int s[16] = {q0.x, q0.y, q0.z, q0.w, q1.x, q1.y, q1.z, q1.w,
                     q2.x, q2.y, q2.z, q2.w, q3.x, q3.y, q3.z, q3.w};
        f16x4 v[16];
#pragma unroll
        for (int u = 0; u < 16; ++u)
          v[u] = *(const f16x4*)(H + (size_t)s[u] * 128 + ll * 4);
#pragma unroll
        for (int u = 0; u < 16; ++u) {
          a0 += (float)v[u][0]; a1 += (float)v[u][1];
          a2 += (float)v[u][2]; a3 += (float)v[u][3];
        }
      }
      for (; e + 4 <= e1; e += 4) {
        int4 qq4 = *(const int4*)(elist + e);
        int s[4] = {qq4.x, qq4.y, qq4.z, qq4.w};
        f16x4 v[4];
#pragma unroll
        for (int u = 0; u < 4; ++u)
          v[u] = *(const f16x4*)(H + (size_t)s[u] * 128 + ll * 4);
#pragma unroll
        for (int u = 0; u < 4; ++u) {
          a0 += (float)v[u][0]; a1 += (float)v[u][1];
          a2 += (float)v[u][2]; a3 += (float)v[u][3];
        }
      }
      for (; e < e1; ++e) {
        f16x4 v = *(const f16x4*)(H + (size_t)elist[e] * 128 + ll * 4);
        a0 += (float)v[0]; a1 += (float)v[1];
        a2 += (float)v[2]; a3 += (float)v[3];
      }
      float inv = 1.0f / (float)max(d, 1);
      f16x4 o;
      o[0] = (_Float16)(a0 * inv); o[1] = (_Float16)(a1 * inv);
      o[2] = (_Float16)(a2 * inv); o[3] = (_Float16)(a3 * inv);
      *(f16x4*)&Af[kb][q * 16 + r][j] = o;
    }
  }
  __syncthreads();

  // phase 2: GEMM. Wave w covers cols w*32..w*32+31; 16 rows.
  const int lane = t & 63;
  const int w = t >> 6;
  const int n16 = lane & 15;
  const int qq = lane >> 4;
  const int colbase = w * 32;

  f32x4 acc[2];
  acc[0] = (f32x4){0.f, 0.f, 0.f, 0.f};
  acc[1] = (f32x4){0.f, 0.f, 0.f, 0.f};

#pragma unroll
  for (int kb = 0; kb < 8; ++kb) {
    f16x8 a = *(const f16x8*)&Af[kb][lane][0];
#pragma unroll
    for (int ct = 0; ct < 2; ++ct) {
      const int ctg = w * 2 + ct;
      f16x8 b = *(const f16x8*)(Wf + ((size_t)(ctg * 8 + kb) * 64 + lane) * 8);
      acc[ct] = __builtin_amdgcn_mfma_f32_16x16x32_f16(a, b, acc[ct], 0, 0, 0);
    }
  }

  // C/D layout: col = lane&15, row = (lane>>4)*4 + reg
#pragma unroll
  for (int r = 0; r < 4; ++r) {
    int row = rowbase + qq * 4 + r;
    unsigned mw = MK[(size_t)row * 4 + w];
#pragma unroll
    for (int ct = 0; ct < 2; ++ct) {
      const int col = colbase + ct * 16 + n16;
      float v = fmaxf(acc[ct][r] + bias[col], 0.f);
      v = ((mw >> (ct * 16 + n16)) & 1u) ? v * (1.0f / 0.7f) : 0.0f;
      outp[(size_t)row * 128 + col] = (_Float16)v;
    }
  }
}

// ---------------- fused layer 1 + layer-2 GEMM ----------------------------
// Same phases as fused_layer, but h1 is never written to global: epilogue
// writes relu+dropout h1 (f16) into Zf LDS tile [16][136], sync, then the
// layer-2 GEMM (K=128, 8 MFMAs/wave) against wfZ -> Y2 (f16) + F (f32).
__global__ __launch_bounds__(256, 8) void fused_layerZ_kernel(
    const _Float16* __restrict__ H, const int* __restrict__ offs,
    const int* __restrict__ deg, const int* __restrict__ elist,
    const _Float16* __restrict__ Wf, const float* __restrict__ bias,
    const unsigned* __restrict__ MK, const _Float16* __restrict__ WfZ,
    const float* __restrict__ bl2, _Float16* __restrict__ Y2,
    float* __restrict__ F) {
  __shared__ __align__(16) _Float16 Af[8][64][8];      // 8 KB
  __shared__ __align__(16) _Float16 Zf[16][136];       // 4.25 KB (16B-aligned rows)
  const int t = threadIdx.x;
  const int rowbase = blockIdx.x * 16;

  // phase 1a: own H rows -> Af[4..7]
  {
    int r = t >> 4, o = t & 15;
    f16x8 v = *(const f16x8*)(H + (size_t)(rowbase + r) * 128 + o * 8);
    *(f16x8*)&Af[4 + (o >> 2)][(o & 3) * 16 + r][0] = v;
  }

  // phase 1b: gather-mean -> Af[0..3]
  {
    const int hw = t >> 5;
    const int ll = t & 31;
    const int kb = ll >> 3, q = (ll >> 1) & 3, j = (ll & 1) * 4;
#pragma unroll 1
    for (int i = 0; i < 2; ++i) {
      int r = hw * 2 + i;
      int node = rowbase + r;
      float a0 = 0.f, a1 = 0.f, a2 = 0.f, a3 = 0.f;
      const int e0 = offs[node];
      const int d = deg[node];
      const int e1 = e0 + d;
      int e = e0;
      for (; e + 16 <= e1; e += 16) {
        int4 q0 = *(const int4*)(elist + e);
        int4 q1 = *(const int4*)(elist + e + 4);
        int4 q2 = *(const int4*)(elist + e + 8);
        int4 q3 = *(const int4*)(elist + e + 12);
        int s[16] = {q0.x, q0.y, q0.z, q0.w, q1.x, q1.y, q1.z, q1.w,
                     q2.x, q2.y, q2.z, q2.w, q3.x, q3.y, q3.z, q3.w};
        f16x4 v[16];
#pragma unroll
        for (int u = 0; u < 16; ++u)
          v[u] = *(const f16x4*)(H + (size_t)s[u] * 128 + ll * 4);
#pragma unroll
        for (int u = 0; u < 16; ++u) {
          a0 += (float)v[u][0]; a1 += (float)v[u][1];
          a2 += (float)v[u][2]; a3 += (float)v[u][3];
        }
      }
      for (; e + 4 <= e1; e += 4) {
        int4 qq4 = *(const int4*)(elist + e);
        int s[4] = {qq4.x, qq4.y, qq4.z, qq4.w};
        f16x4 v[4];
#pragma unroll
        for (int u = 0; u < 4; ++u)
          v[u] = *(const f16x4*)(H + (size_t)s[u] * 128 + ll * 4);
#pragma unroll
        for (int u = 0; u < 4; ++u) {
          a0 += (float)v[u][0]; a1 += (float)v[u][1];
          a2 += (float)v[u][2]; a3 += (float)v[u][3];
        }
      }
      for (; e < e1; ++e) {
        f16x4 v = *(const f16x4*)(H + (size_t)elist[e] * 128 + ll * 4);
        a0 += (float)v[0]; a1 += (float)v[1];
        a2 += (float)v[2]; a3 += (float)v[3];
      }
      float inv = 1.0f / (float)max(d, 1);
      f16x4 o;
      o[0] = (_Float16)(a0 * inv); o[1] = (_Float16)(a1 * inv);
      o[2] = (_Float16)(a2 * inv); o[3] = (_Float16)(a3 * inv);
      *(f16x4*)&Af[kb][q * 16 + r][j] = o;
    }
  }
  __syncthreads();

  // phase 2: layer-1 GEMM (K=256)
  const int lane = t & 63;
  const int w = t >> 6;
  const int n16 = lane & 15;
  const int qq = lane >> 4;
  const int colbase = w * 32;

  f32x4 acc[2];
  acc[0] = (f32x4){0.f, 0.f, 0.f, 0.f};
  acc[1] = (f32x4){0.f, 0.f, 0.f, 0.f};

#pragma unroll
  for (int kb = 0; kb < 8; ++kb) {
    f16x8 a = *(const f16x8*)&Af[kb][lane][0];
#pragma unroll
    for (int ct = 0; ct < 2; ++ct) {
      const int ctg = w * 2 + ct;
      f16x8 b = *(const f16x8*)(Wf + ((size_t)(ctg * 8 + kb) * 64 + lane) * 8);
      acc[ct] = __builtin_amdgcn_mfma_f32_16x16x32_f16(a, b, acc[ct], 0, 0, 0);
    }
  }

  // epilogue: h1 = dropout(relu(acc+bias)) -> Zf[row][col] (f16, row-major)
#pragma unroll
  for (int r = 0; r < 4; ++r) {
    int row = qq * 4 + r;                 // local 0..15
    unsigned mw = MK[(size_t)(rowbase + row) * 4 + w];
#pragma unroll
    for (int ct = 0; ct < 2; ++ct) {
      const int col = colbase + ct * 16 + n16;
      float v = fmaxf(acc[ct][r] + bias[col], 0.f);
      v = ((mw >> (ct * 16 + n16)) & 1u) ? v * (1.0f / 0.7f) : 0.0f;
      Zf[row][col] = (_Float16)v;
    }
  }
  __syncthreads();

  // layer-2 GEMM: A = Zf rows (K=128), B = WfZ; wave w -> cols w*32..+31
  f32x4 az[2];
  az[0] = (f32x4){0.f, 0.f, 0.f, 0.f};
  az[1] = (f32x4){0.f, 0.f, 0.f, 0.f};
#pragma unroll
  for (int kb = 0; kb < 4; ++kb) {
    f16x8 a = *(const f16x8*)&Zf[n16][kb * 32 + qq * 8];
#pragma unroll
    for (int ct = 0; ct < 2; ++ct) {
      const int ctg = w * 2 + ct;
      f16x8 b = *(const f16x8*)(WfZ + ((size_t)(ctg * 4 + kb) * 64 + lane) * 8);
      az[ct] = __builtin_amdgcn_mfma_f32_16x16x32_f16(a, b, az[ct], 0, 0, 0);
    }
  }
#pragma unroll
  for (int ct = 0; ct < 2; ++ct) {
    const int col = colbase + ct * 16 + n16;   // 0..127
#pragma unroll
    for (int r = 0; r < 4; ++r) {
      int row = rowbase + qq * 4 + r;
      float v = az[ct][r];
      if (col < 64) Y2[(size_t)row * 64 + col] = (_Float16)v;
      else F[(size_t)row * 64 + (col - 64)] = v + bl2[col - 64];
    }
  }
}

// ---------------- gather64 + final add: out = F + mean(Y2[nbrs]) ----------
__global__ __launch_bounds__(256) void gather64_add_kernel(
    const _Float16* __restrict__ Y2, const float* __restrict__ F,
    const int* __restrict__ offs, const int* __restrict__ deg,
    const int* __restrict__ elist, float* __restrict__ out) {
  int node = blockIdx.x * 8 + (threadIdx.x >> 5);
  if (node >= N) return;
  int l = threadIdx.x & 31;
  const int e0 = offs[node];              // e0 % 4 == 0
  const int d = deg[node];
  const int e1 = e0 + d;
  float a0 = 0.f, a1 = 0.f;
  int e = e0;
  for (; e + 16 <= e1; e += 16) {
    int4 q0 = *(const int4*)(elist + e);
    int4 q1 = *(const int4*)(elist + e + 4);
    int4 q2 = *(const int4*)(elist + e + 8);
    int4 q3 = *(const int4*)(elist + e + 12);
    int s[16] = {q0.x, q0.y, q0.z, q0.w, q1.x, q1.y, q1.z, q1.w,
                 q2.x, q2.y, q2.z, q2.w, q3.x, q3.y, q3.z, q3.w};
    f16x2 v[16];
#pragma unroll
    for (int u = 0; u < 16; ++u)
      v[u] = *(const f16x2*)(Y2 + (size_t)s[u] * 64 + l * 2);
#pragma unroll
    for (int u = 0; u < 16; ++u) { a0 += (float)v[u][0]; a1 += (float)v[u][1]; }
  }
  for (; e + 4 <= e1; e += 4) {
    int4 q = *(const int4*)(elist + e);
    int s[4] = {q.x, q.y, q.z, q.w};
    f16x2 v[4];
#pragma unroll
    for (int u = 0; u < 4; ++u)
      v[u] = *(const f16x2*)(Y2 + (size_t)s[u] * 64 + l * 2);
#pragma unroll
    for (int u = 0; u < 4; ++u) { a0 += (float)v[u][0]; a1 += (float)v[u][1]; }
  }
  for (; e < e1; ++e) {
    f16x2 v = *(const f16x2*)(Y2 + (size_t)elist[e] * 64 + l * 2);
    a0 += (float)v[0]; a1 += (float)v[1];
  }
  float inv = 1.0f / (float)max(d, 1);
  float2 f = ((const float2*)(F + (size_t)node * 64))[l];
  float2 o;
  o.x = f.x + a0 * inv;
  o.y = f.y + a1 * inv;
  ((float2*)(out + (size_t)node * 64))[l] = o;
}

extern "C" void kernel_launch(void* const* d_in, const int* in_sizes, int n_in,
                              void* d_out, int out_size, void* d_ws, size_t ws_size,
                              hipStream_t stream) {
  const float* x   = (const float*)d_in[0];
  const float* u1  = (const float*)d_in[1];
  const float* u2  = (const float*)d_in[2];
  const float* wl0 = (const float*)d_in[3];
  const float* bl0 = (const float*)d_in[4];
  const float* wr0 = (const float*)d_in[5];
  const float* wl1 = (const float*)d_in[6];
  const float* bl1 = (const float*)d_in[7];
  const float* wr1 = (const float*)d_in[8];
  const float* wl2 = (const float*)d_in[9];
  const float* bl2 = (const float*)d_in[10];
  const float* wr2 = (const float*)d_in[11];
  const int* edge  = (const int*)d_in[12];
  const int* src = edge;
  const int* dst = edge + E;

  // workspace layout
  _Float16* HA  = (_Float16*)d_ws;                 // N x 128 f16
  _Float16* HB  = HA + (size_t)N * 128;            // N x 128 f16
  _Float16* M16 = HB + (size_t)N * 128;            // N x 128 f16 (Y2)
  float* F      = (float*)(M16 + (size_t)N * 128); // N x 64 f32
  int* offs     = (int*)(F + (size_t)N * 64);      // N
  int* deg      = offs + N;                        // N
  int* elist    = deg + N;                         // NBUCK*SLOT (padded)
  unsigned* T   = (unsigned*)(elist + NBUCK * SLOT);
  int* bcur     = (int*)(T + NBUCK * SLOT);        // NBUCK (counts)
  uintptr_t p = (uintptr_t)(bcur + NBUCK);
  p = (p + 15) & ~(uintptr_t)15;
  _Float16* wf0 = (_Float16*)p;                    // 8*8*512
  _Float16* wf1 = wf0 + 8 * 8 * 512;
  _Float16* wfZ = wf1 + 8 * 8 * 512;               // 8*4*512
  unsigned* mk1 = (unsigned*)(wfZ + 8 * 4 * 512);  // N*4 u32 (bit mask)
  unsigned* mk2 = mk1 + (size_t)N * 4;             // N*4 u32

  // 0) bcur counts = 0
  hipMemsetAsync(bcur, 0, NBUCK * sizeof(int), stream);
  // 1) merged setup + scatter
  setup_scatter_kernel<<<NEB + CONVB + 320, 256, 0, stream>>>(
      src, dst, bcur, T, x, wl0, wr0, wl1, wr1, wl2, wr2, HA, wf0, wf1, wfZ);
  // 2) place (+ mask build streamed on idle CUs)
  bucket_place_kernel<<<NBUCK + 2 * MASKB, 256, 0, stream>>>(
      T, bcur, u1, u2, mk1, mk2, offs, deg, elist);

  const int GM16 = N / 16;             // 3125 fused-layer blocks
  const int GG64 = (N + 7) / 8;        // half-wave per node

  // ---- Layer 0 (fused gather+GEMM) ----
  fused_layer_kernel<<<GM16, 256, 0, stream>>>(HA, offs, deg, elist, wf0, bl0,
                                               mk1, HB);
  // ---- Layer 1 + Layer-2 GEMM (fused; h1 never hits global) ----
  fused_layerZ_kernel<<<GM16, 256, 0, stream>>>(HB, offs, deg, elist, wf1, bl1,
                                                mk2, wfZ, bl2, M16, F);
  // ---- Layer 2 gather + add ----
  gather64_add_kernel<<<GG64, 256, 0, stream>>>(M16, F, offs, deg, elist,
                                                (float*)d_out);
}